// Round 7
// baseline (36831.903 us; speedup 1.0000x reference)
//
#include <hip/hip_runtime.h>

#define Tn 512
#define In 40
#define Hn 256
#define Kn 4
#define On 16
#define ROWS 16
#define NGRP 64

typedef _Float16 half8  __attribute__((ext_vector_type(8)));
typedef _Float16 half2v __attribute__((ext_vector_type(2)));
typedef float    f32x4  __attribute__((ext_vector_type(4)));

union UH { uint4 u; half8 h; half2v h2[4]; };

static __device__ __forceinline__ float tanh_fast(float x) {
    float e = __expf(2.f * x);
    return 1.f - 2.f * __builtin_amdgcn_rcpf(e + 1.f);
}

// ---------------------------------------------------------------------------
// B-fragment pack (R3-validated layout). frag f = (m*10 + s)*16 + t.
//   s = 0..1  : input-proj K-slices (k = s*32.., In=40 padded to 64 w/ zeros)
//   s = 2..9  : recurrent K-slices  (j = (s-2)*32..)
// Lane l holds B[k=(l>>4)*8+j][n = l&15], col n = m*256 + t*16 + (l&15),
// stored as 8 contiguous fp16 at WPB[f*512 + l*8].
// ---------------------------------------------------------------------------
__global__ void pack_frags(const float* __restrict__ Wr, const float* __restrict__ Wi,
                           _Float16* __restrict__ WPB) {
    const int f = blockIdx.x;          // 0..639
    const int l = threadIdx.x;         // 0..63
    const int m = f / 160, rem = f - m * 160;
    const int s = rem >> 4, t = rem & 15;
    const int n = m * 256 + t * 16 + (l & 15);
    const int kloc = (l >> 4) * 8;
    half8 v;
    if (s < 2) {
#pragma unroll
        for (int j = 0; j < 8; j++) {
            const int k = s * 32 + kloc + j;
            v[j] = (k < In) ? (_Float16)Wi[n * In + k] : (_Float16)0.f;
        }
    } else {
#pragma unroll
        for (int j = 0; j < 8; j++)
            v[j] = (_Float16)Wr[(size_t)n * Hn + (s - 2) * 32 + kloc + j];
    }
    *(half8*)(WPB + (size_t)f * 512 + l * 8) = v;
}

#define FI(g, mm, sl)      (((g) * 4 + (mm)) * 2 + (sl))
#define LBI(g, mm, sl, r)  ((((g) * 4 + (mm)) * 2 + (sl)) * 16 + (r))
#define OBI(g, mm, sl, r)  (((size_t)(((g) * 4 + (mm)) * 2 + (sl)) * 16 + (r)) * 256)

// ---------------------------------------------------------------------------
// Cooperative kernel: 256 blocks (= 64 groups x 4 compartments) x 512 thr.
// Block (g,m): rows [g*16, g*16+16), cols [m*256, (m+1)*256). Rec B-frags
// (128 KB) LDS-resident; input B-frags (4/wave) streamed from L2 per step.
// Per step: MFMA outs -> publish outs+logit partials -> flag(release) ->
// spin(acquire) on 4 peers -> read 4 contribs -> softmax -> h_new (redundant).
// 2-slot ping-pong; LDS 149 KB forces 1 block/CU; co-op launch guarantees
// co-residency (deadlock-free).
// ---------------------------------------------------------------------------
__global__ __launch_bounds__(512) void diru_coop(
    const float* __restrict__ x,
    const _Float16* __restrict__ WPB,
    const float* __restrict__ b_in, const float* __restrict__ b_rec,
    const float* __restrict__ W_gate, const float* __restrict__ b_gate,
    const float* __restrict__ W_fc, const float* __restrict__ b_fc,
    _Float16* __restrict__ Obuf, float* __restrict__ Lbuf,
    int* __restrict__ flags, float* __restrict__ out)
{
    const int tid = threadIdx.x;
    const int l   = tid & 63;
    const int w   = tid >> 6;          // wave 0..7
    const int lm  = l & 15;            // row / col-in-tile
    const int lq  = l >> 4;            // k-quad
    const int bid = blockIdx.x;
    const int g   = bid >> 2, m = bid & 3;
    const int b0  = g * ROWS;
    const int t2a = 2 * w, t2b = 2 * w + 1;   // this wave's two tiles

    __shared__ _Float16 fragsR[8 * 16 * 512];   // 128 KB rec B-frags [s8][t][l*8]
    __shared__ _Float16 hh_s[ROWS * 256];       // 8 KB h, rows 512B, swizzled
    __shared__ _Float16 xs_s[ROWS * 64];        // 2 KB x (pad->64), rows 128B, swz
    __shared__ _Float16 outs_s[ROWS * 256];     // 8 KB outs, rows 512B, swizzled
    __shared__ float    red[8][16][4];          // logit partials per wave
    __shared__ float    lg_s[4][16][4];         // staged peer logit partials

    const uint4* __restrict__ WPB4 = (const uint4*)WPB;

    // ---- prologue: rec frags -> LDS (128 KB contiguous) ----
    {
        uint4* fr4 = (uint4*)fragsR;
        const int base = (m * 10 + 2) * 16 * 64;   // uint4 units
#pragma unroll
        for (int k = 0; k < 16; k++)
            fr4[k * 512 + tid] = WPB4[base + k * 512 + tid];
    }

    // ---- gate B-frag (slice w of this block's 256 cols), biases ----
    half8 gb = {};
    if (lm < Kn) {
#pragma unroll
        for (int j = 0; j < 8; j++)
            gb[j] = (_Float16)W_gate[lm * 1024 + m * 256 + w * 32 + lq * 8 + j];
    }
    const int colA = m * 256 + t2a * 16 + lm;
    const int colB = m * 256 + t2b * 16 + lm;
    const float biasA = b_in[colA] + b_rec[colA];
    const float biasB = b_in[colB] + b_rec[colB];
    float bg4[4];
#pragma unroll
    for (int kg = 0; kg < 4; kg++) bg4[kg] = b_gate[kg];

    // ---- zero hh/xs, stage x(0) ----
    for (int i = tid; i < ROWS * 256; i += 512) hh_s[i] = (_Float16)0.f;
    for (int i = tid; i < ROWS * 64;  i += 512) xs_s[i] = (_Float16)0.f;

    const int xi0_r = tid / In, xi0_i = tid - xi0_r * In;
    const int has2  = (tid + 512) < ROWS * In;     // tid < 128
    const int t1i   = tid + 512;
    const int xi1_r = t1i / In, xi1_i = t1i - xi1_r * In;
    const int xsb0 = xi0_r * 128 + (((((xi0_i * 2) >> 4) ^ (xi0_r & 7)) << 4) | ((xi0_i * 2) & 15));
    const int xsb1 = xi1_r * 128 + (((((xi1_i * 2) >> 4) ^ (xi1_r & 7)) << 4) | ((xi1_i * 2) & 15));
    const float* xp0 = x + ((size_t)(b0 + xi0_r) * Tn) * In + xi0_i;
    const float* xp1 = x + ((size_t)(b0 + xi1_r) * Tn) * In + xi1_i;
    *(_Float16*)((char*)xs_s + xsb0) = (_Float16)xp0[0];
    if (has2) *(_Float16*)((char*)xs_s + xsb1) = (_Float16)xp1[0];

    __syncthreads();

    for (int t = 1; t <= Tn; t++) {
        const int sl = t & 1;

        // ---- stream this step's input B-frags (4 x uint4, L2-resident) ----
        const uint4 bx0a = WPB4[((m * 10 + 0) * 16 + t2a) * 64 + l];
        const uint4 bx0b = WPB4[((m * 10 + 0) * 16 + t2b) * 64 + l];
        const uint4 bx1a = WPB4[((m * 10 + 1) * 16 + t2a) * 64 + l];
        const uint4 bx1b = WPB4[((m * 10 + 1) * 16 + t2b) * 64 + l];

        // ---- compute: 2 input + 8 rec slices, 2 tiles ----
        f32x4 accA, accB;
        accA[0] = biasA; accA[1] = biasA; accA[2] = biasA; accA[3] = biasA;
        accB[0] = biasB; accB[1] = biasB; accB[2] = biasB; accB[3] = biasB;

        const half8 ax0 = *(const half8*)((const char*)xs_s + lm * 128 + ((lq ^ (lm & 7)) << 4));
        const half8 ax1 = *(const half8*)((const char*)xs_s + lm * 128 + (((4 + lq) ^ (lm & 7)) << 4));
        { UH c; c.u = bx0a; accA = __builtin_amdgcn_mfma_f32_16x16x32_f16(ax0, c.h, accA, 0, 0, 0); }
        { UH c; c.u = bx0b; accB = __builtin_amdgcn_mfma_f32_16x16x32_f16(ax0, c.h, accB, 0, 0, 0); }
        { UH c; c.u = bx1a; accA = __builtin_amdgcn_mfma_f32_16x16x32_f16(ax1, c.h, accA, 0, 0, 0); }
        { UH c; c.u = bx1b; accB = __builtin_amdgcn_mfma_f32_16x16x32_f16(ax1, c.h, accB, 0, 0, 0); }

#pragma unroll
        for (int s8 = 0; s8 < 8; s8++) {
            const int slot = s8 * 4 + lq;
            const half8 ah = *(const half8*)((const char*)hh_s + lm * 512 + ((slot ^ (lm & 7)) << 4));
            const half8 bA = *(const half8*)((const char*)fragsR + (size_t)(s8 * 16 + t2a) * 1024 + l * 16);
            const half8 bB = *(const half8*)((const char*)fragsR + (size_t)(s8 * 16 + t2b) * 1024 + l * 16);
            accA = __builtin_amdgcn_mfma_f32_16x16x32_f16(ah, bA, accA, 0, 0, 0);
            accB = __builtin_amdgcn_mfma_f32_16x16x32_f16(ah, bB, accB, 0, 0, 0);
        }

        // ---- tanh + write outs (swizzled) ----
#pragma unroll
        for (int q = 0; q < 4; q++) {
            const int row = lq * 4 + q;
            const int cba = t2a * 32 + lm * 2, cbb = t2b * 32 + lm * 2;
            *(_Float16*)((char*)outs_s + row * 512 + ((((cba >> 4) ^ (row & 7)) << 4) | (cba & 15)))
                = (_Float16)tanh_fast(accA[q]);
            *(_Float16*)((char*)outs_s + row * 512 + ((((cbb >> 4) ^ (row & 7)) << 4) | (cbb & 15)))
                = (_Float16)tanh_fast(accB[q]);
        }
        __syncthreads();   // B1: outs ready

        // ---- publish outs to Obuf (coalesced) + logit MFMA ----
        {
            const int row = tid >> 5, s32 = tid & 31;
            const uint4 v = *(const uint4*)((const char*)outs_s + row * 512 + ((s32 ^ (row & 7)) << 4));
            *(uint4*)(Obuf + OBI(g, m, sl, row) + s32 * 8) = v;
        }
        {
            const int slot = w * 4 + lq;
            const half8 ga = *(const half8*)((const char*)outs_s + lm * 512 + ((slot ^ (lm & 7)) << 4));
            f32x4 z; z[0] = 0.f; z[1] = 0.f; z[2] = 0.f; z[3] = 0.f;
            const f32x4 gacc = __builtin_amdgcn_mfma_f32_16x16x32_f16(ga, gb, z, 0, 0, 0);
            if (lm < 4) {
#pragma unroll
                for (int q = 0; q < 4; q++) red[w][lq * 4 + q][lm] = gacc[q];
            }
        }
        __syncthreads();   // B2: red ready, Obuf stores issued

        if (tid < 64) {
            const int r = tid >> 2, kg = tid & 3;
            float s = 0.f;
#pragma unroll
            for (int s8 = 0; s8 < 8; s8++) s += red[s8][r][kg];
            Lbuf[LBI(g, m, sl, r) * 4 + kg] = s;
        }
        __threadfence();
        __syncthreads();   // B3: all global stores fenced
        if (tid == 0)
            __hip_atomic_store(&flags[FI(g, m, sl)], t, __ATOMIC_RELEASE, __HIP_MEMORY_SCOPE_AGENT);

        // ---- prefetch next x while waiting ----
        float xp0v = 0.f, xp1v = 0.f;
        if (t < Tn) {
            xp0v = xp0[(size_t)t * In];
            if (has2) xp1v = xp1[(size_t)t * In];
        }

        if (tid < 4) {
            while (__hip_atomic_load(&flags[FI(g, tid, sl)], __ATOMIC_ACQUIRE,
                                     __HIP_MEMORY_SCOPE_AGENT) < t)
                __builtin_amdgcn_s_sleep(1);
        }
        __syncthreads();   // B4: all 4 peers ready
        // per-wave acquire so every wave's view is invalidated
        (void)__hip_atomic_load(&flags[FI(g, tid & 3, sl)], __ATOMIC_ACQUIRE,
                                __HIP_MEMORY_SCOPE_AGENT);

        if (tid < 256) {
            const int mm = tid >> 6, r = (tid >> 2) & 15, kg = tid & 3;
            lg_s[mm][r][kg] = Lbuf[LBI(g, mm, sl, r) * 4 + kg];
        }
        __syncthreads();   // B5: logit partials staged

        // ---- softmax + h_new (redundant per thread; 32 thr/row) ----
        {
            const int r = tid >> 5, c32 = tid & 31;
            float lg[4];
#pragma unroll
            for (int kg = 0; kg < 4; kg++)
                lg[kg] = bg4[kg] + lg_s[0][r][kg] + lg_s[1][r][kg] + lg_s[2][r][kg] + lg_s[3][r][kg];
            const float mx = fmaxf(fmaxf(lg[0], lg[1]), fmaxf(lg[2], lg[3]));
            const float e0 = __expf(lg[0] - mx), e1 = __expf(lg[1] - mx);
            const float e2 = __expf(lg[2] - mx), e3 = __expf(lg[3] - mx);
            const float inv = __builtin_amdgcn_rcpf(e0 + e1 + e2 + e3);
            const float wf[4] = { e0 * inv, e1 * inv, e2 * inv, e3 * inv };
            half2v wg2[4];
#pragma unroll
            for (int mm = 0; mm < 4; mm++) {
                const _Float16 h = (_Float16)wf[mm];
                half2v v2; v2[0] = h; v2[1] = h; wg2[mm] = v2;
            }
            half2v hn0 = {}, hn1 = {}, hn2 = {}, hn3 = {};
#pragma unroll
            for (int mm = 0; mm < 4; mm++) {
                UH ov;
                ov.u = *(const uint4*)(Obuf + OBI(g, mm, sl, r) + c32 * 8);
                hn0 = hn0 + ov.h2[0] * wg2[mm];
                hn1 = hn1 + ov.h2[1] * wg2[mm];
                hn2 = hn2 + ov.h2[2] * wg2[mm];
                hn3 = hn3 + ov.h2[3] * wg2[mm];
            }
            UH pk; pk.h2[0] = hn0; pk.h2[1] = hn1; pk.h2[2] = hn2; pk.h2[3] = hn3;
            *(uint4*)((char*)hh_s + r * 512 + ((c32 ^ (r & 7)) << 4)) = pk.u;
        }

        // ---- stage x(t) for next step ----
        if (t < Tn) {
            *(_Float16*)((char*)xs_s + xsb0) = (_Float16)xp0v;
            if (has2) *(_Float16*)((char*)xs_s + xsb1) = (_Float16)xp1v;
        }
        __syncthreads();   // B6: hh/xs ready for next step
    }

    // ---- final FC (block m==0 of each group writes output) ----
    if (m == 0 && tid < ROWS * On) {
        const int r = tid >> 4, o = tid & 15;
        float s = b_fc[o];
#pragma unroll 4
        for (int j8 = 0; j8 < 32; j8++) {
            const half8 hv = *(const half8*)((const char*)hh_s + r * 512 + ((j8 ^ (r & 7)) << 4));
#pragma unroll
            for (int jj = 0; jj < 8; jj++)
                s = fmaf((float)hv[jj], W_fc[o * Hn + j8 * 8 + jj], s);
        }
        out[(size_t)(b0 + r) * On + o] = s;
    }
}

extern "C" void kernel_launch(void* const* d_in, const int* in_sizes, int n_in,
                              void* d_out, int out_size, void* d_ws, size_t ws_size,
                              hipStream_t stream) {
    const float* x      = (const float*)d_in[0];
    const float* W_in   = (const float*)d_in[1];
    const float* b_in   = (const float*)d_in[2];
    const float* W_rec  = (const float*)d_in[3];
    const float* b_rec  = (const float*)d_in[4];
    const float* W_gate = (const float*)d_in[5];
    const float* b_gate = (const float*)d_in[6];
    const float* W_fc   = (const float*)d_in[7];
    const float* b_fc   = (const float*)d_in[8];
    float* out = (float*)d_out;

    char* ws = (char*)d_ws;
    _Float16* WPB   = (_Float16*)(ws);                    // 640 KB
    _Float16* Obuf  = (_Float16*)(ws + (1u << 20));       // 4 MB
    float*    Lbuf  = (float*)   (ws + (5u << 20));       // 128 KB
    int*      flags = (int*)     (ws + (5u << 20) + (1u << 18));  // 2 KB

    hipMemsetAsync(flags, 0, NGRP * 4 * 2 * sizeof(int), stream);
    pack_frags<<<640, 64, 0, stream>>>(W_rec, W_in, WPB);

    void* kargs[] = { (void*)&x, (void*)&WPB, (void*)&b_in, (void*)&b_rec,
                      (void*)&W_gate, (void*)&b_gate, (void*)&W_fc, (void*)&b_fc,
                      (void*)&Obuf, (void*)&Lbuf, (void*)&flags, (void*)&out };
    hipLaunchCooperativeKernel((void*)diru_coop, dim3(256), dim3(512),
                               kargs, 0, stream);
}

// Round 8
// 6066.391 us; speedup vs baseline: 6.0715x; 6.0715x over previous
//
#include <hip/hip_runtime.h>

#define Tn 512
#define In 40
#define Hn 256
#define Kn 4
#define On 16
#define ROWS 16
#define NBLK 64

typedef _Float16 half8  __attribute__((ext_vector_type(8)));
typedef _Float16 half2v __attribute__((ext_vector_type(2)));
typedef float    f32x4  __attribute__((ext_vector_type(4)));

union UH { uint4 u; half8 h; half2v h2[4]; };

static __device__ __forceinline__ float tanh_fast(float x) {
    float e = __expf(2.f * x);
    return 1.f - 2.f * __builtin_amdgcn_rcpf(e + 1.f);
}

// async global->LDS, 16B per lane: HW writes lane i at ldsbase + i*16,
// global source address is per-lane (we pass base + l*16).
static __device__ __forceinline__ void gll16(const void* g, void* l) {
    __builtin_amdgcn_global_load_lds(
        (const __attribute__((address_space(1))) void*)g,
        (__attribute__((address_space(3))) void*)l, 16, 0, 0);
}

// raw barrier: drain LDS ops only; leave global_load_lds (vmcnt) in flight
#define BAR() do { asm volatile("s_waitcnt lgkmcnt(0)" ::: "memory"); \
                   __builtin_amdgcn_s_barrier(); } while (0)

// ---------------------------------------------------------------------------
// B-fragment pack (R3-validated): frag f = w*80 + s*8 + t  (wave, slice, tile)
//   s = 0..1 : input K-slices (In=40 padded to 64 with zeros)
//   s = 2..9 : recurrent K-slices (j = (s-2)*32 ..)
// Lane l holds B[k=(l>>4)*8+j][n = w*128 + t*16 + (l&15)], 8 fp16 at
// WPB[(f*64 + l)*8].
// ---------------------------------------------------------------------------
__global__ void pack_frags(const float* __restrict__ Wr, const float* __restrict__ Wi,
                           _Float16* __restrict__ WPB) {
    const int f = blockIdx.x;          // 0..639
    const int l = threadIdx.x;         // 0..63
    const int w = f / 80;
    const int rem = f - w * 80;
    const int s = rem >> 3, t = rem & 7;
    const int n = w * 128 + t * 16 + (l & 15);
    const int kloc = (l >> 4) * 8;
    half8 v;
    if (s < 2) {
#pragma unroll
        for (int j = 0; j < 8; j++) {
            const int k = s * 32 + kloc + j;
            v[j] = (k < In) ? (_Float16)Wi[n * In + k] : (_Float16)0.f;
        }
    } else {
#pragma unroll
        for (int j = 0; j < 8; j++)
            v[j] = (_Float16)Wr[(size_t)n * Hn + (s - 2) * 32 + kloc + j];
    }
    *(half8*)(WPB + ((size_t)f * 64 + l) * 8) = v;
}

// ---------------------------------------------------------------------------
// 64 blocks x 512 thr (8 waves). Wave w owns cols [w*128, w*128+128) = 8 tiles.
// Input slices 0,1 register-resident; rec slices 2..9 streamed via
// global_load_lds into per-wave triple-buffered staging (16 phases x 4 frags,
// counted vmcnt, loads cross barriers). LDS ~140 KB -> 1 block/CU.
// ---------------------------------------------------------------------------
__global__ __launch_bounds__(512) void diru_pipe(
    const float* __restrict__ x,
    const _Float16* __restrict__ WPB,
    const float* __restrict__ b_in, const float* __restrict__ b_rec,
    const float* __restrict__ W_gate, const float* __restrict__ b_gate,
    const float* __restrict__ W_fc, const float* __restrict__ b_fc,
    float* __restrict__ out)
{
    const int tid = threadIdx.x;
    const int l   = tid & 63;
    const int w   = tid >> 6;
    const int lm  = l & 15;
    const int lq  = l >> 4;
    const int b0  = blockIdx.x * ROWS;

    __shared__ _Float16 hh_s[ROWS * 256];            // 8 KB, swizzled
    __shared__ _Float16 xs_s[ROWS * 64];             // 2 KB, swizzled (pad->64)
    __shared__ _Float16 outs_s[ROWS * 1024];         // 32 KB, swizzled
    __shared__ float    red[8 * ROWS * 4];           // 2 KB
    __shared__ __align__(16) char stage[8][3][4096]; // 96 KB staging

    const uint4* __restrict__ WPB4 = (const uint4*)WPB;
    const char*  __restrict__ WPBc = (const char*)WPB;

    // ---- register-resident input B-frags (slices 0,1) ----
    half8 rb0[8], rb1[8];
#pragma unroll
    for (int t8 = 0; t8 < 8; t8++) {
        UH c0; c0.u = WPB4[(size_t)(w * 80 + 0 * 8 + t8) * 64 + l]; rb0[t8] = c0.h;
        UH c1; c1.u = WPB4[(size_t)(w * 80 + 1 * 8 + t8) * 64 + l]; rb1[t8] = c1.h;
    }

    // ---- gate B-frag, biases ----
    half8 gb[4];
#pragma unroll
    for (int s2 = 0; s2 < 4; s2++) {
        half8 g = {};
        if (lm < Kn) {
#pragma unroll
            for (int j = 0; j < 8; j++)
                g[j] = (_Float16)W_gate[lm * 1024 + w * 128 + s2 * 32 + lq * 8 + j];
        }
        gb[s2] = g;
    }
    float bias[8];
#pragma unroll
    for (int t8 = 0; t8 < 8; t8++) {
        const int n = w * 128 + t8 * 16 + lm;
        bias[t8] = b_in[n] + b_rec[n];
    }
    float bg4[4];
#pragma unroll
    for (int kg = 0; kg < 4; kg++) bg4[kg] = b_gate[kg];

    // ---- zero hh/xs, stage x(0) ----
    for (int i = tid; i < ROWS * 256; i += 512) hh_s[i] = (_Float16)0.f;
    for (int i = tid; i < ROWS * 64;  i += 512) xs_s[i] = (_Float16)0.f;

    const int xi0_r = tid / In, xi0_i = tid - xi0_r * In;
    const int has2  = (tid + 512) < ROWS * In;     // tid < 128
    const int t1i   = tid + 512;
    const int xi1_r = t1i / In, xi1_i = t1i - xi1_r * In;
    const int xsb0 = xi0_r * 128 + (((((xi0_i * 2) >> 4) ^ (xi0_r & 7)) << 4) | ((xi0_i * 2) & 15));
    const int xsb1 = xi1_r * 128 + (((((xi1_i * 2) >> 4) ^ (xi1_r & 7)) << 4) | ((xi1_i * 2) & 15));
    const float* xp0 = x + ((size_t)(b0 + xi0_r) * Tn) * In + xi0_i;
    const float* xp1 = x + ((size_t)(b0 + xi1_r) * Tn) * In + xi1_i;
    *(_Float16*)((char*)xs_s + xsb0) = (_Float16)xp0[0];
    if (has2) *(_Float16*)((char*)xs_s + xsb1) = (_Float16)xp1[0];

    const int r_c  = tid >> 5;         // phase-C row
    const int c32  = tid & 31;
    const int swzC = (r_c & 7);

    for (int t = 0; t < Tn; t++) {
        // ---- x prefetch + first 3 stream phases (before barrier; in-order
        //      vmcnt retirement makes counted waits below safe) ----
        float xr0 = 0.f, xr1 = 0.f;
        if (t + 1 < Tn) {
            xr0 = xp0[(size_t)(t + 1) * In];
            if (has2) xr1 = xp1[(size_t)(t + 1) * In];
        }
#pragma unroll
        for (int p = 0; p < 3; p++) {
            const int f0 = w * 80 + (2 + (p >> 1)) * 8 + (p & 1) * 4;
#pragma unroll
            for (int f = 0; f < 4; f++)
                gll16(WPBc + (size_t)(f0 + f) * 1024 + l * 16, &stage[w][p][f * 1024]);
        }

        BAR();   // hh(t), xs(t) ready; stream loads stay in flight

        f32x4 acc[8];
#pragma unroll
        for (int t8 = 0; t8 < 8; t8++) {
            f32x4 a; a[0] = bias[t8]; a[1] = bias[t8]; a[2] = bias[t8]; a[3] = bias[t8];
            acc[t8] = a;
        }

        // ---- resident input slices ----
        const half8 ax0 = *(const half8*)((const char*)xs_s + lm * 128 + (((0 + lq) ^ (lm & 7)) << 4));
        const half8 ax1 = *(const half8*)((const char*)xs_s + lm * 128 + (((4 + lq) ^ (lm & 7)) << 4));
#pragma unroll
        for (int t8 = 0; t8 < 8; t8++)
            acc[t8] = __builtin_amdgcn_mfma_f32_16x16x32_f16(ax0, rb0[t8], acc[t8], 0, 0, 0);
#pragma unroll
        for (int t8 = 0; t8 < 8; t8++)
            acc[t8] = __builtin_amdgcn_mfma_f32_16x16x32_f16(ax1, rb1[t8], acc[t8], 0, 0, 0);

        // ---- streamed rec slices: 16 phases, triple buffer, counted vmcnt ----
        half8 ah = {};
#pragma unroll
        for (int p = 0; p < 16; p++) {
            if (p <= 13)      asm volatile("s_waitcnt vmcnt(8)" ::: "memory");
            else if (p == 14) asm volatile("s_waitcnt vmcnt(4)" ::: "memory");
            else              asm volatile("s_waitcnt vmcnt(0)" ::: "memory");
            const int s = 2 + (p >> 1);
            if ((p & 1) == 0)
                ah = *(const half8*)((const char*)hh_s + lm * 512 + ((((s - 2) * 4 + lq) ^ (lm & 7)) << 4));
#pragma unroll
            for (int f = 0; f < 4; f++) {
                const half8 bf = *(const half8*)(&stage[w][p % 3][f * 1024 + l * 16]);
                acc[(p & 1) * 4 + f] =
                    __builtin_amdgcn_mfma_f32_16x16x32_f16(ah, bf, acc[(p & 1) * 4 + f], 0, 0, 0);
            }
            if (p + 3 <= 15) {
                const int pn = p + 3;
                const int f0 = w * 80 + (2 + (pn >> 1)) * 8 + (pn & 1) * 4;
#pragma unroll
                for (int f = 0; f < 4; f++)
                    gll16(WPBc + (size_t)(f0 + f) * 1024 + l * 16, &stage[w][pn % 3][f * 1024]);
            }
        }

        // ---- tanh + outs write (swizzled, wave-own cols) ----
#pragma unroll
        for (int t8 = 0; t8 < 8; t8++) {
            const int colb = w * 256 + t8 * 32 + lm * 2;
            const int slot = colb >> 4;
#pragma unroll
            for (int q = 0; q < 4; q++) {
                const int row = lq * 4 + q;
                *(_Float16*)((char*)outs_s + row * 2048 + (((slot ^ (row & 7)) << 4) | (colb & 15)))
                    = (_Float16)tanh_fast(acc[t8][q]);
            }
        }

        // ---- gate logits (wave-own outs chunk; same-wave LDS ordering) ----
        {
            f32x4 gacc = {0.f, 0.f, 0.f, 0.f};
#pragma unroll
            for (int s2 = 0; s2 < 4; s2++) {
                const int slot = w * 16 + s2 * 4 + lq;
                const half8 ga = *(const half8*)((const char*)outs_s + lm * 2048 + ((slot ^ (lm & 7)) << 4));
                gacc = __builtin_amdgcn_mfma_f32_16x16x32_f16(ga, gb[s2], gacc, 0, 0, 0);
            }
            if (lm < 4) {
#pragma unroll
                for (int q = 0; q < 4; q++)
                    red[(w * 16 + (lq * 4 + q)) * 4 + lm] = gacc[q];
            }
        }

        BAR();   // outs + red visible to all waves

        // ---- softmax + h_new + x stage ----
        {
            float lg0 = bg4[0], lg1 = bg4[1], lg2 = bg4[2], lg3 = bg4[3];
#pragma unroll
            for (int w2 = 0; w2 < 8; w2++) {
                const f32x4 v = *(const f32x4*)&red[(w2 * 16 + r_c) * 4];
                lg0 += v[0]; lg1 += v[1]; lg2 += v[2]; lg3 += v[3];
            }
            const float mx = fmaxf(fmaxf(lg0, lg1), fmaxf(lg2, lg3));
            const float e0 = __expf(lg0 - mx), e1 = __expf(lg1 - mx);
            const float e2 = __expf(lg2 - mx), e3 = __expf(lg3 - mx);
            const float inv = __builtin_amdgcn_rcpf(e0 + e1 + e2 + e3);
            half2v wg2[4];
            {
                const float wf[4] = { e0 * inv, e1 * inv, e2 * inv, e3 * inv };
#pragma unroll
                for (int k = 0; k < 4; k++) {
                    const _Float16 h = (_Float16)wf[k];
                    half2v v2; v2[0] = h; v2[1] = h; wg2[k] = v2;
                }
            }
            half2v hn[4] = {};
#pragma unroll
            for (int k = 0; k < 4; k++) {
                const int slot = k * 32 + c32;
                UH ov;
                ov.h = *(const half8*)((const char*)outs_s + r_c * 2048 + ((slot ^ swzC) << 4));
#pragma unroll
                for (int pp = 0; pp < 4; pp++)
                    hn[pp] = hn[pp] + ov.h2[pp] * wg2[k];
            }
            UH ho;
#pragma unroll
            for (int pp = 0; pp < 4; pp++) ho.h2[pp] = hn[pp];
            *(uint4*)((char*)hh_s + r_c * 512 + ((c32 ^ swzC) << 4)) = ho.u;
        }
        if (t + 1 < Tn) {
            *(_Float16*)((char*)xs_s + xsb0) = (_Float16)xr0;
            if (has2) *(_Float16*)((char*)xs_s + xsb1) = (_Float16)xr1;
        }
        // loop-top BAR orders hh/xs writes vs next step's reads
    }

    BAR();
    // ---- final FC ----
    if (tid < ROWS * On) {
        const int r = tid >> 4, o = tid & 15;
        float s = b_fc[o];
#pragma unroll 4
        for (int j8 = 0; j8 < 32; j8++) {
            const half8 hv = *(const half8*)((const char*)hh_s + r * 512 + ((j8 ^ (r & 7)) << 4));
#pragma unroll
            for (int jj = 0; jj < 8; jj++)
                s = fmaf((float)hv[jj], W_fc[o * Hn + j8 * 8 + jj], s);
        }
        out[(size_t)(b0 + r) * On + o] = s;
    }
}

extern "C" void kernel_launch(void* const* d_in, const int* in_sizes, int n_in,
                              void* d_out, int out_size, void* d_ws, size_t ws_size,
                              hipStream_t stream) {
    const float* x      = (const float*)d_in[0];
    const float* W_in   = (const float*)d_in[1];
    const float* b_in   = (const float*)d_in[2];
    const float* W_rec  = (const float*)d_in[3];
    const float* b_rec  = (const float*)d_in[4];
    const float* W_gate = (const float*)d_in[5];
    const float* b_gate = (const float*)d_in[6];
    const float* W_fc   = (const float*)d_in[7];
    const float* b_fc   = (const float*)d_in[8];
    float* out = (float*)d_out;

    _Float16* WPB = (_Float16*)d_ws;   // 640 frags * 1 KB = 640 KB

    pack_frags<<<640, 64, 0, stream>>>(W_rec, W_in, WPB);
    diru_pipe<<<NBLK, 512, 0, stream>>>(x, WPB, b_in, b_rec,
                                        W_gate, b_gate, W_fc, b_fc, out);
}

// Round 10
// 6002.589 us; speedup vs baseline: 6.1360x; 1.0106x over previous
//
#include <hip/hip_runtime.h>

#define Tn 512
#define In 40
#define Hn 256
#define Kn 4
#define On 16
#define ROWS 16
#define NBLK 64

typedef _Float16 half8  __attribute__((ext_vector_type(8)));
typedef _Float16 half2v __attribute__((ext_vector_type(2)));
typedef float    f32x4  __attribute__((ext_vector_type(4)));

union UH { uint4 u; half8 h; half2v h2[4]; };

static __device__ __forceinline__ float tanh_fast(float x) {
    float e = __expf(2.f * x);
    return 1.f - 2.f * __builtin_amdgcn_rcpf(e + 1.f);
}

// async global->LDS, 16B per lane: HW writes lane i at ldsbase + i*16,
// global source address is per-lane (we pass base + l*16).
static __device__ __forceinline__ void gll16(const void* g, void* l) {
    __builtin_amdgcn_global_load_lds(
        (const __attribute__((address_space(1))) void*)g,
        (__attribute__((address_space(3))) void*)l, 16, 0, 0);
}

// raw barrier: drain LDS ops only; leave global_load_lds (vmcnt) in flight
#define BAR() do { asm volatile("s_waitcnt lgkmcnt(0)" ::: "memory"); \
                   __builtin_amdgcn_s_barrier(); } while (0)

// ---------------------------------------------------------------------------
// B-fragment pack (R3/R8-validated, byte-identical): frag f = w*80 + s*8 + t.
//   s = 0..1 : input K-slices (In=40 padded to 64 with zeros)
//   s = 2..9 : recurrent K-slices (j = (s-2)*32 ..)
// Lane l holds B[k=(l>>4)*8+j][n = w*128 + t*16 + (l&15)], 8 fp16 at
// WPB[(f*64 + l)*8].
// ---------------------------------------------------------------------------
__global__ void pack_frags(const float* __restrict__ Wr, const float* __restrict__ Wi,
                           _Float16* __restrict__ WPB) {
    const int f = blockIdx.x;          // 0..639
    const int l = threadIdx.x;         // 0..63
    const int w = f / 80;
    const int rem = f - w * 80;
    const int s = rem >> 3, t = rem & 7;
    const int n = w * 128 + t * 16 + (l & 15);
    const int kloc = (l >> 4) * 8;
    half8 v;
    if (s < 2) {
#pragma unroll
        for (int j = 0; j < 8; j++) {
            const int k = s * 32 + kloc + j;
            v[j] = (k < In) ? (_Float16)Wi[n * In + k] : (_Float16)0.f;
        }
    } else {
#pragma unroll
        for (int j = 0; j < 8; j++)
            v[j] = (_Float16)Wr[(size_t)n * Hn + (s - 2) * 32 + kloc + j];
    }
    *(half8*)(WPB + ((size_t)f * 64 + l) * 8) = v;
}

// ---------------------------------------------------------------------------
// R8 template, unchanged: 64 blocks x 512 thr (8 waves). Wave w owns cols
// [w*128, w*128+128) = 8 tiles. Input slices 0,1 register-resident; rec
// slices 2..9 streamed via global_load_lds (16 phases x 4 frags, triple
// buffer, counted vmcnt).  SINGLE DELTA vs R8: streamed-slice order rotated
// per block by rot = (bid>>3)&7, so the 8 co-XCD blocks (bid = c mod 8 under
// round-robin dispatch) read 8 DIFFERENT 64-KB slice regions at any instant
// -> de-lockstep the L2 bank access pattern. Pure bijective reorder of the
// accumulation; pipeline/barrier/vmcnt structure byte-identical to R8.
// ---------------------------------------------------------------------------
__global__ __launch_bounds__(512) void diru_pipe(
    const float* __restrict__ x,
    const _Float16* __restrict__ WPB,
    const float* __restrict__ b_in, const float* __restrict__ b_rec,
    const float* __restrict__ W_gate, const float* __restrict__ b_gate,
    const float* __restrict__ W_fc, const float* __restrict__ b_fc,
    float* __restrict__ out)
{
    const int tid = threadIdx.x;
    const int l   = tid & 63;
    const int w   = tid >> 6;
    const int lm  = l & 15;
    const int lq  = l >> 4;
    const int b0  = blockIdx.x * ROWS;
    const int rot = (int)((blockIdx.x >> 3) & 7);   // de-lockstep rotation

    __shared__ _Float16 hh_s[ROWS * 256];            // 8 KB, swizzled
    __shared__ _Float16 xs_s[ROWS * 64];             // 2 KB, swizzled (pad->64)
    __shared__ _Float16 outs_s[ROWS * 1024];         // 32 KB, swizzled
    __shared__ float    red[8 * ROWS * 4];           // 2 KB
    __shared__ __align__(16) char stage[8][3][4096]; // 96 KB staging

    const uint4* __restrict__ WPB4 = (const uint4*)WPB;
    const char*  __restrict__ WPBc = (const char*)WPB;

    // ---- register-resident input B-frags (slices 0,1) ----
    half8 rb0[8], rb1[8];
#pragma unroll
    for (int t8 = 0; t8 < 8; t8++) {
        UH c0; c0.u = WPB4[(size_t)(w * 80 + 0 * 8 + t8) * 64 + l]; rb0[t8] = c0.h;
        UH c1; c1.u = WPB4[(size_t)(w * 80 + 1 * 8 + t8) * 64 + l]; rb1[t8] = c1.h;
    }

    // ---- gate B-frag, biases ----
    half8 gb[4];
#pragma unroll
    for (int s2 = 0; s2 < 4; s2++) {
        half8 g = {};
        if (lm < Kn) {
#pragma unroll
            for (int j = 0; j < 8; j++)
                g[j] = (_Float16)W_gate[lm * 1024 + w * 128 + s2 * 32 + lq * 8 + j];
        }
        gb[s2] = g;
    }
    float bias[8];
#pragma unroll
    for (int t8 = 0; t8 < 8; t8++) {
        const int n = w * 128 + t8 * 16 + lm;
        bias[t8] = b_in[n] + b_rec[n];
    }
    float bg4[4];
#pragma unroll
    for (int kg = 0; kg < 4; kg++) bg4[kg] = b_gate[kg];

    // ---- zero hh/xs, stage x(0) ----
    for (int i = tid; i < ROWS * 256; i += 512) hh_s[i] = (_Float16)0.f;
    for (int i = tid; i < ROWS * 64;  i += 512) xs_s[i] = (_Float16)0.f;

    const int xi0_r = tid / In, xi0_i = tid - xi0_r * In;
    const int has2  = (tid + 512) < ROWS * In;     // tid < 128
    const int t1i   = tid + 512;
    const int xi1_r = t1i / In, xi1_i = t1i - xi1_r * In;
    const int xsb0 = xi0_r * 128 + (((((xi0_i * 2) >> 4) ^ (xi0_r & 7)) << 4) | ((xi0_i * 2) & 15));
    const int xsb1 = xi1_r * 128 + (((((xi1_i * 2) >> 4) ^ (xi1_r & 7)) << 4) | ((xi1_i * 2) & 15));
    const float* xp0 = x + ((size_t)(b0 + xi0_r) * Tn) * In + xi0_i;
    const float* xp1 = x + ((size_t)(b0 + xi1_r) * Tn) * In + xi1_i;
    *(_Float16*)((char*)xs_s + xsb0) = (_Float16)xp0[0];
    if (has2) *(_Float16*)((char*)xs_s + xsb1) = (_Float16)xp1[0];

    const int r_c  = tid >> 5;         // phase-C row
    const int c32  = tid & 31;
    const int swzC = (r_c & 7);

    for (int t = 0; t < Tn; t++) {
        // ---- x prefetch + first 3 stream phases (before barrier; in-order
        //      vmcnt retirement makes counted waits below safe) ----
        float xr0 = 0.f, xr1 = 0.f;
        if (t + 1 < Tn) {
            xr0 = xp0[(size_t)(t + 1) * In];
            if (has2) xr1 = xp1[(size_t)(t + 1) * In];
        }
#pragma unroll
        for (int p = 0; p < 3; p++) {
            const int f0 = w * 80 + (2 + (((p >> 1) + rot) & 7)) * 8 + (p & 1) * 4;
#pragma unroll
            for (int f = 0; f < 4; f++)
                gll16(WPBc + (size_t)(f0 + f) * 1024 + l * 16, &stage[w][p][f * 1024]);
        }

        BAR();   // hh(t), xs(t) ready; stream loads stay in flight

        f32x4 acc[8];
#pragma unroll
        for (int t8 = 0; t8 < 8; t8++) {
            f32x4 a; a[0] = bias[t8]; a[1] = bias[t8]; a[2] = bias[t8]; a[3] = bias[t8];
            acc[t8] = a;
        }

        // ---- resident input slices ----
        const half8 ax0 = *(const half8*)((const char*)xs_s + lm * 128 + (((0 + lq) ^ (lm & 7)) << 4));
        const half8 ax1 = *(const half8*)((const char*)xs_s + lm * 128 + (((4 + lq) ^ (lm & 7)) << 4));
#pragma unroll
        for (int t8 = 0; t8 < 8; t8++)
            acc[t8] = __builtin_amdgcn_mfma_f32_16x16x32_f16(ax0, rb0[t8], acc[t8], 0, 0, 0);
#pragma unroll
        for (int t8 = 0; t8 < 8; t8++)
            acc[t8] = __builtin_amdgcn_mfma_f32_16x16x32_f16(ax1, rb1[t8], acc[t8], 0, 0, 0);

        // ---- streamed rec slices (rotated order): 16 phases, triple buffer ----
        half8 ah = {};
#pragma unroll
        for (int p = 0; p < 16; p++) {
            if (p <= 13)      asm volatile("s_waitcnt vmcnt(8)" ::: "memory");
            else if (p == 14) asm volatile("s_waitcnt vmcnt(4)" ::: "memory");
            else              asm volatile("s_waitcnt vmcnt(0)" ::: "memory");
            const int sIdx = ((p >> 1) + rot) & 7;   // rec slice 2+sIdx
            if ((p & 1) == 0)
                ah = *(const half8*)((const char*)hh_s + lm * 512 + (((sIdx * 4 + lq) ^ (lm & 7)) << 4));
#pragma unroll
            for (int f = 0; f < 4; f++) {
                const half8 bf = *(const half8*)(&stage[w][p % 3][f * 1024 + l * 16]);
                acc[(p & 1) * 4 + f] =
                    __builtin_amdgcn_mfma_f32_16x16x32_f16(ah, bf, acc[(p & 1) * 4 + f], 0, 0, 0);
            }
            if (p + 3 <= 15) {
                const int pn = p + 3;
                const int f0 = w * 80 + (2 + (((pn >> 1) + rot) & 7)) * 8 + (pn & 1) * 4;
#pragma unroll
                for (int f = 0; f < 4; f++)
                    gll16(WPBc + (size_t)(f0 + f) * 1024 + l * 16, &stage[w][pn % 3][f * 1024]);
            }
        }

        // ---- tanh + outs write (swizzled, wave-own cols) ----
#pragma unroll
        for (int t8 = 0; t8 < 8; t8++) {
            const int colb = w * 256 + t8 * 32 + lm * 2;
            const int slot = colb >> 4;
#pragma unroll
            for (int q = 0; q < 4; q++) {
                const int row = lq * 4 + q;
                *(_Float16*)((char*)outs_s + row * 2048 + (((slot ^ (row & 7)) << 4) | (colb & 15)))
                    = (_Float16)tanh_fast(acc[t8][q]);
            }
        }

        // ---- gate logits (wave-own outs chunk; same-wave LDS ordering) ----
        {
            f32x4 gacc = {0.f, 0.f, 0.f, 0.f};
#pragma unroll
            for (int s2 = 0; s2 < 4; s2++) {
                const int slot = w * 16 + s2 * 4 + lq;
                const half8 ga = *(const half8*)((const char*)outs_s + lm * 2048 + ((slot ^ (lm & 7)) << 4));
                gacc = __builtin_amdgcn_mfma_f32_16x16x32_f16(ga, gb[s2], gacc, 0, 0, 0);
            }
            if (lm < 4) {
#pragma unroll
                for (int q = 0; q < 4; q++)
                    red[(w * 16 + (lq * 4 + q)) * 4 + lm] = gacc[q];
            }
        }

        BAR();   // outs + red visible to all waves

        // ---- softmax + h_new + x stage ----
        {
            float lg0 = bg4[0], lg1 = bg4[1], lg2 = bg4[2], lg3 = bg4[3];
#pragma unroll
            for (int w2 = 0; w2 < 8; w2++) {
                const f32x4 v = *(const f32x4*)&red[(w2 * 16 + r_c) * 4];
                lg0 += v[0]; lg1 += v[1]; lg2 += v[2]; lg3 += v[3];
            }
            const float mx = fmaxf(fmaxf(lg0, lg1), fmaxf(lg2, lg3));
            const float e0 = __expf(lg0 - mx), e1 = __expf(lg1 - mx);
            const float e2 = __expf(lg2 - mx), e3 = __expf(lg3 - mx);
            const float inv = __builtin_amdgcn_rcpf(e0 + e1 + e2 + e3);
            half2v wg2[4];
            {
                const float wf[4] = { e0 * inv, e1 * inv, e2 * inv, e3 * inv };
#pragma unroll
                for (int k = 0; k < 4; k++) {
                    const _Float16 h = (_Float16)wf[k];
                    half2v v2; v2[0] = h; v2[1] = h; wg2[k] = v2;
                }
            }
            half2v hn[4] = {};
#pragma unroll
            for (int k = 0; k < 4; k++) {
                const int slot = k * 32 + c32;
                UH ov;
                ov.h = *(const half8*)((const char*)outs_s + r_c * 2048 + ((slot ^ swzC) << 4));
#pragma unroll
                for (int pp = 0; pp < 4; pp++)
                    hn[pp] = hn[pp] + ov.h2[pp] * wg2[k];
            }
            UH ho;
#pragma unroll
            for (int pp = 0; pp < 4; pp++) ho.h2[pp] = hn[pp];
            *(uint4*)((char*)hh_s + r_c * 512 + ((c32 ^ swzC) << 4)) = ho.u;
        }
        if (t + 1 < Tn) {
            *(_Float16*)((char*)xs_s + xsb0) = (_Float16)xr0;
            if (has2) *(_Float16*)((char*)xs_s + xsb1) = (_Float16)xr1;
        }
        // loop-top BAR orders hh/xs writes vs next step's reads
    }

    BAR();
    // ---- final FC ----
    if (tid < ROWS * On) {
        const int r = tid >> 4, o = tid & 15;
        float s = b_fc[o];
#pragma unroll 4
        for (int j8 = 0; j8 < 32; j8++) {
            const half8 hv = *(const half8*)((const char*)hh_s + r * 512 + ((j8 ^ (r & 7)) << 4));
#pragma unroll
            for (int jj = 0; jj < 8; jj++)
                s = fmaf((float)hv[jj], W_fc[o * Hn + j8 * 8 + jj], s);
        }
        out[(size_t)(b0 + r) * On + o] = s;
    }
}

extern "C" void kernel_launch(void* const* d_in, const int* in_sizes, int n_in,
                              void* d_out, int out_size, void* d_ws, size_t ws_size,
                              hipStream_t stream) {
    const float* x      = (const float*)d_in[0];
    const float* W_in   = (const float*)d_in[1];
    const float* b_in   = (const float*)d_in[2];
    const float* W_rec  = (const float*)d_in[3];
    const float* b_rec  = (const float*)d_in[4];
    const float* W_gate = (const float*)d_in[5];
    const float* b_gate = (const float*)d_in[6];
    const float* W_fc   = (const float*)d_in[7];
    const float* b_fc   = (const float*)d_in[8];
    float* out = (float*)d_out;

    _Float16* WPB = (_Float16*)d_ws;   // 640 frags * 1 KB = 640 KB

    pack_frags<<<640, 64, 0, stream>>>(W_rec, W_in, WPB);
    diru_pipe<<<NBLK, 512, 0, stream>>>(x, WPB, b_in, b_rec,
                                        W_gate, b_gate, W_fc, b_fc, out);
}